// Round 1
// baseline (2282.871 us; speedup 1.0000x reference)
//
#include <hip/hip_runtime.h>

#define D 128
#define EDIMC 16
#define HEADS 8
#define HD 16

__device__ __forceinline__ unsigned enc_f(float f){
    unsigned u = __float_as_uint(f);
    return (u & 0x80000000u) ? ~u : (u | 0x80000000u);
}
__device__ __forceinline__ float dec_f(unsigned e){
    return (e & 0x80000000u) ? __uint_as_float(e & 0x7fffffffu)
                             : __uint_as_float(~e);
}

// ---------------- degree ----------------
__global__ void deg_count(const int* __restrict__ row, int E, float* __restrict__ deg){
    int i = blockIdx.x*blockDim.x + threadIdx.x;
    if(i < E) atomicAdd(&deg[row[i]], 1.0f);
}
__global__ void deg_fin(float* __restrict__ deg, float* __restrict__ dis, int N){
    int i = blockIdx.x*blockDim.x + threadIdx.x;
    if(i < N){ float d = deg[i] + 1.0f; deg[i] = d; dis[i] = rsqrtf(d); }
}

// ---------------- generic fp32 GEMM: C = A(MxK) @ B(KxN) [+ bias] ----------------
// BM=64, BN=64, BK=16, 256 threads, 4x4 microtile. K%16==0, N%64==0 required.
__global__ __launch_bounds__(256) void gemm_bias(
    const float* __restrict__ A, const float* __restrict__ B,
    const float* __restrict__ bias, float* __restrict__ C,
    int M, int K, int Nc)
{
    __shared__ float As[16][65];
    __shared__ float Bs[16][65];
    int tid = threadIdx.x;
    int bm = blockIdx.y*64, bn = blockIdx.x*64;
    int ty = tid/16, tx = tid%16;
    int arow = tid>>2, akq = (tid&3)*4;     // A: 64 rows x 16 k, float4 per thread
    int brow = tid>>4, bcq = (tid&15)*4;    // B: 16 rows x 64 cols
    float acc[4][4] = {};
    for(int k0 = 0; k0 < K; k0 += 16){
        float4 av = make_float4(0,0,0,0);
        if(bm + arow < M)
            av = *(const float4*)&A[(size_t)(bm+arow)*K + k0 + akq];
        float4 bv = *(const float4*)&B[(size_t)(k0+brow)*Nc + bn + bcq];
        As[akq+0][arow]=av.x; As[akq+1][arow]=av.y;
        As[akq+2][arow]=av.z; As[akq+3][arow]=av.w;
        Bs[brow][bcq+0]=bv.x; Bs[brow][bcq+1]=bv.y;
        Bs[brow][bcq+2]=bv.z; Bs[brow][bcq+3]=bv.w;
        __syncthreads();
        #pragma unroll
        for(int kk = 0; kk < 16; kk++){
            float a0=As[kk][ty*4+0], a1=As[kk][ty*4+1], a2=As[kk][ty*4+2], a3=As[kk][ty*4+3];
            float b0=Bs[kk][tx*4+0], b1=Bs[kk][tx*4+1], b2=Bs[kk][tx*4+2], b3=Bs[kk][tx*4+3];
            acc[0][0]+=a0*b0; acc[0][1]+=a0*b1; acc[0][2]+=a0*b2; acc[0][3]+=a0*b3;
            acc[1][0]+=a1*b0; acc[1][1]+=a1*b1; acc[1][2]+=a1*b2; acc[1][3]+=a1*b3;
            acc[2][0]+=a2*b0; acc[2][1]+=a2*b1; acc[2][2]+=a2*b2; acc[2][3]+=a2*b3;
            acc[3][0]+=a3*b0; acc[3][1]+=a3*b1; acc[3][2]+=a3*b2; acc[3][3]+=a3*b3;
        }
        __syncthreads();
    }
    #pragma unroll
    for(int i = 0; i < 4; i++){
        int r = bm + ty*4 + i;
        if(r >= M) continue;
        #pragma unroll
        for(int j = 0; j < 4; j++){
            int c = bn + tx*4 + j;
            C[(size_t)r*Nc + c] = acc[i][j] + (bias ? bias[c] : 0.0f);
        }
    }
}

// ---------------- GCN edge messages: agg[col] += norm * relu(hlin[row] + ea@We + be) ----------------
__global__ __launch_bounds__(256) void gcn_msg(
    const float* __restrict__ hlin, const int* __restrict__ row, const int* __restrict__ col,
    const float* __restrict__ eattr, const float* __restrict__ We, const float* __restrict__ be,
    const float* __restrict__ dis, float* __restrict__ agg, int E)
{
    __shared__ float sWe[EDIMC*D];
    __shared__ float sbe[D];
    int tid = threadIdx.x;
    for(int i = tid; i < EDIMC*D; i += 256) sWe[i] = We[i];
    if(tid < D) sbe[tid] = be[tid];
    __syncthreads();
    int sub = tid >> 7;      // 0/1 : which edge of the pair
    int c   = tid & 127;     // feature column
    int e0  = blockIdx.x * 32;
    for(int it = 0; it < 16; ++it){
        int e = e0 + it*2 + sub;
        if(e >= E) continue;
        int r = row[e], cl = col[e];
        const float* ea = &eattr[(size_t)e*EDIMC];
        float ev = sbe[c];
        #pragma unroll
        for(int k = 0; k < EDIMC; k++) ev += ea[k]*sWe[k*D + c];
        float m = dis[r]*dis[cl]*fmaxf(hlin[(size_t)r*D + c] + ev, 0.0f);
        atomicAdd(&agg[(size_t)cl*D + c], m);
    }
}

// ---------------- combine: out = relu(agg + relu(hlin+root)/deg); write h_cur + xc block ----------------
__global__ void gcn_combine(
    const float* __restrict__ agg, const float* __restrict__ hlin,
    const float* __restrict__ root, const float* __restrict__ deg,
    float* __restrict__ xc, float* __restrict__ hcur, int N, int blk)
{
    int idx = blockIdx.x*blockDim.x + threadIdx.x;
    if(idx >= N*D) return;
    int i = idx >> 7, c = idx & 127;
    float v = agg[idx] + fmaxf(hlin[idx] + root[c], 0.0f)/deg[i];
    v = fmaxf(v, 0.0f);
    hcur[idx] = v;
    xc[(size_t)i*512 + (size_t)blk*128 + c] = v;
}

__global__ void copy_x_to_xc(const float* __restrict__ x, float* __restrict__ xc, int N){
    int idx = blockIdx.x*blockDim.x + threadIdx.x;
    if(idx >= N*D) return;
    int i = idx >> 7, c = idx & 127;
    xc[(size_t)i*512 + c] = x[idx];
}

// ---------------- BN statistics (sum + sumsq per column of xc NxC512) ----------------
__global__ __launch_bounds__(256) void bn_stats(
    const float* __restrict__ xc, int N, float* __restrict__ stats)
{
    int c0 = threadIdx.x;  // owns cols c0 and c0+256
    int rows_per = (N + gridDim.x - 1)/gridDim.x;
    int r0 = blockIdx.x*rows_per, r1 = min(N, r0 + rows_per);
    float s0=0, q0=0, s1=0, q1=0;
    for(int r = r0; r < r1; r++){
        float a = xc[(size_t)r*512 + c0];
        float b = xc[(size_t)r*512 + c0 + 256];
        s0 += a; q0 += a*a; s1 += b; q1 += b*b;
    }
    atomicAdd(&stats[c0], s0);       atomicAdd(&stats[512 + c0], q0);
    atomicAdd(&stats[c0+256], s1);   atomicAdd(&stats[512 + c0 + 256], q1);
}

// fold BN into W_se / b_se
__global__ void fold_wse(const float* __restrict__ Wse, const float* __restrict__ gamma,
                         const float* __restrict__ stats, float Ninv, float* __restrict__ Wse2)
{
    int k = blockIdx.x, j = threadIdx.x;   // 512 blocks x 128 threads
    float mu  = stats[k]*Ninv;
    float var = stats[512+k]*Ninv - mu*mu;
    float sc  = gamma[k]*rsqrtf(var + 1e-5f);
    Wse2[(size_t)k*128 + j] = Wse[(size_t)k*128 + j]*sc;
}
__global__ void fold_bse(const float* __restrict__ Wse, const float* __restrict__ gamma,
                         const float* __restrict__ beta, const float* __restrict__ bse,
                         const float* __restrict__ stats, float Ninv, float* __restrict__ bse2)
{
    int j = threadIdx.x;  // 128
    float acc = bse[j];
    for(int k = 0; k < 512; k++){
        float mu  = stats[k]*Ninv;
        float var = stats[512+k]*Ninv - mu*mu;
        float sc  = gamma[k]*rsqrtf(var + 1e-5f);
        float sh  = beta[k] - mu*sc;
        acc += sh*Wse[(size_t)k*128 + j];
    }
    bse2[j] = acc;
}

// ---------------- attention ----------------
__global__ __launch_bounds__(256) void attn_logits(
    const float* __restrict__ qk, const int* __restrict__ src, const int* __restrict__ dst,
    float* __restrict__ pbuf, unsigned* __restrict__ mbuf, int E)
{
    int idx = blockIdx.x*blockDim.x + threadIdx.x;
    if(idx >= E*HEADS) return;
    int e = idx >> 3, h = idx & 7;
    int s = src[e], d2 = dst[e];
    const float* qj = &qk[(size_t)s*256 + h*HD];
    const float* qi = &qk[(size_t)d2*256 + 128 + h*HD];
    float acc = 0.f;
    #pragma unroll
    for(int k = 0; k < HD; k++) acc += qi[k]*qj[k];
    acc *= 0.25f;   // hd^-0.5, hd=16
    pbuf[idx] = acc;
    atomicMax(&mbuf[(size_t)d2*HEADS + h], enc_f(acc));
}

__global__ __launch_bounds__(256) void attn_exp(
    const int* __restrict__ dst, float* __restrict__ pbuf,
    const unsigned* __restrict__ mbuf, float* __restrict__ sbuf, int E)
{
    int idx = blockIdx.x*blockDim.x + threadIdx.x;
    if(idx >= E*HEADS) return;
    int e = idx >> 3, h = idx & 7;
    int d2 = dst[e];
    float p = expf(pbuf[idx] - dec_f(mbuf[(size_t)d2*HEADS + h]));
    pbuf[idx] = p;
    atomicAdd(&sbuf[(size_t)d2*HEADS + h], p);
}

__global__ __launch_bounds__(256) void attn_out(
    const float* __restrict__ v, const int* __restrict__ src, const int* __restrict__ dst,
    const float* __restrict__ pbuf, const float* __restrict__ sbuf,
    float* __restrict__ out, int E)
{
    int idx = blockIdx.x*blockDim.x + threadIdx.x;
    if(idx >= E*D) return;
    int e = idx >> 7, c = idx & 127;
    int h = c >> 4;
    int sr = src[e], d2 = dst[e];
    float w = pbuf[(size_t)e*HEADS + h] / sbuf[(size_t)d2*HEADS + h];
    atomicAdd(&out[(size_t)d2*D + c], v[(size_t)sr*D + c]*w);
}

extern "C" void kernel_launch(void* const* d_in, const int* in_sizes, int n_in,
                              void* d_out, int out_size, void* d_ws, size_t ws_size,
                              hipStream_t stream)
{
    const float* x     = (const float*)d_in[0];
    const int*   ei    = (const int*)  d_in[1];
    const float* eattr = (const float*)d_in[2];
    const int*   dei   = (const int*)  d_in[3];
    const float* Wv    = (const float*)d_in[4];
    const float* Wqk   = (const float*)d_in[5];
    const float* gW    = (const float*)d_in[6];
    const float* gb    = (const float*)d_in[7];
    const float* groot = (const float*)d_in[8];
    const float* gWe   = (const float*)d_in[9];
    const float* gbe   = (const float*)d_in[10];
    const float* gamma = (const float*)d_in[11];
    const float* beta  = (const float*)d_in[12];
    const float* Wse   = (const float*)d_in[13];
    const float* bse   = (const float*)d_in[14];
    const float* Wout  = (const float*)d_in[15];
    const float* bout  = (const float*)d_in[16];

    const int N = in_sizes[0]/D;
    const int E = in_sizes[1]/2;
    const int L = in_sizes[7]/D;

    float* ws = (float*)d_ws;
    size_t o = 0;
    auto alloc = [&](size_t n){ size_t r = o; o += (n + 63) & ~(size_t)63; return r; };
    size_t f_deg  = alloc((size_t)N);
    size_t f_dis  = alloc((size_t)N);
    size_t f_hcur = alloc((size_t)N*D);    // also reused as attention-out accumulator
    size_t f_hlin = alloc((size_t)N*D);    // also reused as x_struct
    size_t f_agg  = alloc((size_t)N*D);    // also reused as v
    size_t f_xc   = alloc((size_t)N*512);
    size_t f_qk   = alloc((size_t)N*256);
    size_t f_p    = alloc((size_t)E*HEADS);
    size_t f_m    = alloc((size_t)N*HEADS);
    size_t f_s    = alloc((size_t)N*HEADS);
    size_t f_st   = alloc(1024);
    size_t f_w2   = alloc(512*128);
    size_t f_b2   = alloc(128);
    (void)ws_size;

    float* deg  = ws + f_deg;   float* dis = ws + f_dis;
    float* hcur = ws + f_hcur;  float* hlin = ws + f_hlin;
    float* agg  = ws + f_agg;   float* xc = ws + f_xc;
    float* qk   = ws + f_qk;    float* pbuf = ws + f_p;
    unsigned* mbuf = (unsigned*)(ws + f_m);
    float* sbuf = ws + f_s;     float* stats = ws + f_st;
    float* Wse2 = ws + f_w2;    float* bse2 = ws + f_b2;

    const int* e_row = ei;        const int* e_col = ei + E;
    const int* a_src = dei;       const int* a_dst = dei + E;

    dim3 blk256(256);

    // 1. degree + norm
    hipMemsetAsync(deg, 0, (size_t)N*sizeof(float), stream);
    deg_count<<<(E+255)/256, blk256, 0, stream>>>(e_row, E, deg);
    deg_fin<<<(N+255)/256, blk256, 0, stream>>>(deg, dis, N);

    // 2. xc block 0 = x
    copy_x_to_xc<<<((size_t)N*D+255)/256, blk256, 0, stream>>>(x, xc, N);

    // 3. GCN layers
    const float* hin = x;
    for(int l = 0; l < L; l++){
        dim3 g(D/64, (N+63)/64);
        gemm_bias<<<g, blk256, 0, stream>>>(hin, gW + (size_t)l*D*D, gb + (size_t)l*D,
                                            hlin, N, D, D);
        hipMemsetAsync(agg, 0, (size_t)N*D*sizeof(float), stream);
        gcn_msg<<<(E+31)/32, blk256, 0, stream>>>(hlin, e_row, e_col, eattr,
                                                  gWe + (size_t)l*EDIMC*D, gbe + (size_t)l*D,
                                                  dis, agg, E);
        gcn_combine<<<((size_t)N*D+255)/256, blk256, 0, stream>>>(agg, hlin, groot + (size_t)l*D,
                                                                  deg, xc, hcur, N, l+1);
        hin = hcur;
    }

    // 4. BN stats + fold into W_se
    hipMemsetAsync(stats, 0, 1024*sizeof(float), stream);
    bn_stats<<<256, blk256, 0, stream>>>(xc, N, stats);
    float Ninv = 1.0f/(float)N;
    fold_wse<<<512, 128, 0, stream>>>(Wse, gamma, stats, Ninv, Wse2);
    fold_bse<<<1, 128, 0, stream>>>(Wse, gamma, beta, bse, stats, Ninv, bse2);

    // 5. x_struct = xc @ Wse2 + bse2   (into hlin)
    {
        dim3 g(D/64, (N+63)/64);
        gemm_bias<<<g, blk256, 0, stream>>>(xc, Wse2, bse2, hlin, N, 512, D);
    }
    // 6. v = x @ Wv (into agg)
    {
        dim3 g(D/64, (N+63)/64);
        gemm_bias<<<g, blk256, 0, stream>>>(x, Wv, nullptr, agg, N, D, D);
    }
    // 7. qk = x_struct @ Wqk
    {
        dim3 g(256/64, (N+63)/64);
        gemm_bias<<<g, blk256, 0, stream>>>(hlin, Wqk, nullptr, qk, N, D, 256);
    }

    // 8. attention
    hipMemsetAsync(mbuf, 0, (size_t)N*HEADS*sizeof(unsigned), stream);  // enc(-NaN) = 0 = minimum
    hipMemsetAsync(sbuf, 0, (size_t)N*HEADS*sizeof(float), stream);
    hipMemsetAsync(hcur, 0, (size_t)N*D*sizeof(float), stream);         // attention out accumulator
    attn_logits<<<((size_t)E*HEADS+255)/256, blk256, 0, stream>>>(qk, a_src, a_dst, pbuf, mbuf, E);
    attn_exp<<<((size_t)E*HEADS+255)/256, blk256, 0, stream>>>(a_dst, pbuf, mbuf, sbuf, E);
    attn_out<<<((size_t)E*D+255)/256, blk256, 0, stream>>>(agg, a_src, a_dst, pbuf, sbuf, hcur, E);

    // 9. out = attn_out @ Wout + bout
    {
        dim3 g(D/64, (N+63)/64);
        gemm_bias<<<g, blk256, 0, stream>>>(hcur, Wout, bout, (float*)d_out, N, D, D);
    }
}

// Round 2
// 1549.351 us; speedup vs baseline: 1.4734x; 1.4734x over previous
//
#include <hip/hip_runtime.h>

#define D 128
#define EDIMC 16
#define HEADS 8
#define HD 16

// ---------------- degree / histograms ----------------
__global__ void deg_count(const int* __restrict__ row, int E, float* __restrict__ deg){
    int i = blockIdx.x*blockDim.x + threadIdx.x;
    if(i < E) atomicAdd(&deg[row[i]], 1.0f);
}
__global__ void deg_fin(float* __restrict__ deg, float* __restrict__ dis, int N){
    int i = blockIdx.x*blockDim.x + threadIdx.x;
    if(i < N){ float d = deg[i] + 1.0f; deg[i] = d; dis[i] = rsqrtf(d); }
}
__global__ void hist_int(const int* __restrict__ idx, int E, int* __restrict__ cnt){
    int i = blockIdx.x*blockDim.x + threadIdx.x;
    if(i < E) atomicAdd(&cnt[idx[i]], 1);
}

// ---------------- exclusive scan (1 block, 1024 threads, N<=~1M) ----------------
__global__ __launch_bounds__(1024) void scan_excl(const int* __restrict__ cnt, int N, int* __restrict__ off){
    __shared__ int partial[1024];
    int tid = threadIdx.x;
    int chunk = (N + 1023)/1024;
    int lo = tid*chunk, hi = min(N, lo + chunk);
    int s = 0;
    for(int i = lo; i < hi; i++) s += cnt[i];
    partial[tid] = s;
    __syncthreads();
    for(int d = 1; d < 1024; d <<= 1){
        int v = (tid >= d) ? partial[tid-d] : 0;
        __syncthreads();
        partial[tid] += v;
        __syncthreads();
    }
    int run = (tid == 0) ? 0 : partial[tid-1];
    for(int i = lo; i < hi; i++){ off[i] = run; run += cnt[i]; }
    if(tid == 1023) off[N] = run;
}

// ---------------- CSR scatter ----------------
__global__ void scatter_gcn(const int* __restrict__ row, const int* __restrict__ col, int E,
                            const int* __restrict__ goff, int* __restrict__ cur,
                            const float* __restrict__ dis,
                            int* __restrict__ gsrc, int* __restrict__ gedge, float* __restrict__ gnorm){
    int e = blockIdx.x*blockDim.x + threadIdx.x;
    if(e >= E) return;
    int r = row[e], c = col[e];
    int pos = goff[c] + atomicAdd(&cur[c], 1);
    gsrc[pos] = r; gedge[pos] = e; gnorm[pos] = dis[r]*dis[c];
}
__global__ void scatter_attn(const int* __restrict__ src, const int* __restrict__ dst, int E,
                             const int* __restrict__ aoff, int* __restrict__ cur,
                             int* __restrict__ asrc){
    int e = blockIdx.x*blockDim.x + threadIdx.x;
    if(e >= E) return;
    int d2 = dst[e];
    int pos = aoff[d2] + atomicAdd(&cur[d2], 1);
    asrc[pos] = src[e];
}

// ---------------- generic fp32 GEMM: C = A(MxK) @ B(KxN) [+ bias] ----------------
__global__ __launch_bounds__(256) void gemm_bias(
    const float* __restrict__ A, const float* __restrict__ B,
    const float* __restrict__ bias, float* __restrict__ C,
    int M, int K, int Nc)
{
    __shared__ float As[16][65];
    __shared__ float Bs[16][65];
    int tid = threadIdx.x;
    int bm = blockIdx.y*64, bn = blockIdx.x*64;
    int ty = tid/16, tx = tid%16;
    int arow = tid>>2, akq = (tid&3)*4;
    int brow = tid>>4, bcq = (tid&15)*4;
    float acc[4][4] = {};
    for(int k0 = 0; k0 < K; k0 += 16){
        float4 av = make_float4(0,0,0,0);
        if(bm + arow < M)
            av = *(const float4*)&A[(size_t)(bm+arow)*K + k0 + akq];
        float4 bv = *(const float4*)&B[(size_t)(k0+brow)*Nc + bn + bcq];
        As[akq+0][arow]=av.x; As[akq+1][arow]=av.y;
        As[akq+2][arow]=av.z; As[akq+3][arow]=av.w;
        Bs[brow][bcq+0]=bv.x; Bs[brow][bcq+1]=bv.y;
        Bs[brow][bcq+2]=bv.z; Bs[brow][bcq+3]=bv.w;
        __syncthreads();
        #pragma unroll
        for(int kk = 0; kk < 16; kk++){
            float a0=As[kk][ty*4+0], a1=As[kk][ty*4+1], a2=As[kk][ty*4+2], a3=As[kk][ty*4+3];
            float b0=Bs[kk][tx*4+0], b1=Bs[kk][tx*4+1], b2=Bs[kk][tx*4+2], b3=Bs[kk][tx*4+3];
            acc[0][0]+=a0*b0; acc[0][1]+=a0*b1; acc[0][2]+=a0*b2; acc[0][3]+=a0*b3;
            acc[1][0]+=a1*b0; acc[1][1]+=a1*b1; acc[1][2]+=a1*b2; acc[1][3]+=a1*b3;
            acc[2][0]+=a2*b0; acc[2][1]+=a2*b1; acc[2][2]+=a2*b2; acc[2][3]+=a2*b3;
            acc[3][0]+=a3*b0; acc[3][1]+=a3*b1; acc[3][2]+=a3*b2; acc[3][3]+=a3*b3;
        }
        __syncthreads();
    }
    #pragma unroll
    for(int i = 0; i < 4; i++){
        int r = bm + ty*4 + i;
        if(r >= M) continue;
        #pragma unroll
        for(int j = 0; j < 4; j++){
            int c = bn + tx*4 + j;
            C[(size_t)r*Nc + c] = acc[i][j] + (bias ? bias[c] : 0.0f);
        }
    }
}

// ---------------- GCN gather (fused msg + aggregate + combine), 1 block / node ----------------
__global__ __launch_bounds__(128) void gcn_gather(
    const float* __restrict__ hlin, const int* __restrict__ goff,
    const int* __restrict__ gsrc, const int* __restrict__ gedge, const float* __restrict__ gnorm,
    const float* __restrict__ eattr, const float* __restrict__ We, const float* __restrict__ be,
    const float* __restrict__ root, const float* __restrict__ deg,
    float* __restrict__ xc, float* __restrict__ hcur, int blk)
{
    __shared__ float sWe[EDIMC*D];
    int tid = threadIdx.x;
    int node = blockIdx.x;
    for(int i = tid; i < EDIMC*D; i += 128) sWe[i] = We[i];
    __syncthreads();
    int c = tid;
    float bec = be[c];
    float acc = 0.f;
    int s0 = goff[node], s1 = goff[node+1];
    for(int s = s0; s < s1; s++){
        int r  = gsrc[s];
        int ge = gedge[s];
        float nm = gnorm[s];
        const float* ea = &eattr[(size_t)ge*EDIMC];
        float ev = bec;
        #pragma unroll
        for(int k = 0; k < EDIMC; k++) ev += ea[k]*sWe[k*D + c];
        acc += nm*fmaxf(hlin[(size_t)r*D + c] + ev, 0.f);
    }
    float hl = hlin[(size_t)node*D + c];
    float v = acc + fmaxf(hl + root[c], 0.f)/deg[node];
    v = fmaxf(v, 0.f);
    hcur[(size_t)node*D + c] = v;
    xc[(size_t)node*512 + (size_t)blk*D + c] = v;
}

__global__ void copy_x_to_xc(const float* __restrict__ x, float* __restrict__ xc, int N){
    int idx = blockIdx.x*blockDim.x + threadIdx.x;
    if(idx >= N*D) return;
    int i = idx >> 7, c = idx & 127;
    xc[(size_t)i*512 + c] = x[idx];
}

// ---------------- BN statistics ----------------
__global__ __launch_bounds__(256) void bn_stats(
    const float* __restrict__ xc, int N, float* __restrict__ stats)
{
    int c0 = threadIdx.x;
    int rows_per = (N + gridDim.x - 1)/gridDim.x;
    int r0 = blockIdx.x*rows_per, r1 = min(N, r0 + rows_per);
    float s0=0, q0=0, s1=0, q1=0;
    for(int r = r0; r < r1; r++){
        float a = xc[(size_t)r*512 + c0];
        float b = xc[(size_t)r*512 + c0 + 256];
        s0 += a; q0 += a*a; s1 += b; q1 += b*b;
    }
    atomicAdd(&stats[c0], s0);       atomicAdd(&stats[512 + c0], q0);
    atomicAdd(&stats[c0+256], s1);   atomicAdd(&stats[512 + c0 + 256], q1);
}

__global__ void fold_wse(const float* __restrict__ Wse, const float* __restrict__ gamma,
                         const float* __restrict__ stats, float Ninv, float* __restrict__ Wse2)
{
    int k = blockIdx.x, j = threadIdx.x;
    float mu  = stats[k]*Ninv;
    float var = stats[512+k]*Ninv - mu*mu;
    float sc  = gamma[k]*rsqrtf(var + 1e-5f);
    Wse2[(size_t)k*128 + j] = Wse[(size_t)k*128 + j]*sc;
}
__global__ void fold_bse(const float* __restrict__ Wse, const float* __restrict__ gamma,
                         const float* __restrict__ beta, const float* __restrict__ bse,
                         const float* __restrict__ stats, float Ninv, float* __restrict__ bse2)
{
    int j = threadIdx.x;
    float acc = bse[j];
    for(int k = 0; k < 512; k++){
        float mu  = stats[k]*Ninv;
        float var = stats[512+k]*Ninv - mu*mu;
        float sc  = gamma[k]*rsqrtf(var + 1e-5f);
        float sh  = beta[k] - mu*sc;
        acc += sh*Wse[(size_t)k*128 + j];
    }
    bse2[j] = acc;
}

// ---------------- fused attention (online softmax), 1 block / node ----------------
__global__ __launch_bounds__(128) void attn_fused(
    const float* __restrict__ qk, const float* __restrict__ v,
    const int* __restrict__ aoff, const int* __restrict__ asrc,
    float* __restrict__ out, int N)
{
    int node = blockIdx.x;
    int c = threadIdx.x;
    int s0 = aoff[node], s1 = aoff[node+1];
    if(s0 == s1){
        out[(size_t)node*D + c] = 0.f;
        return;
    }
    float qi = qk[(size_t)node*256 + 128 + c];
    float m = -INFINITY, ssum = 0.f, acc = 0.f;
    for(int s = s0; s < s1; s++){
        int sr = asrc[s];
        float prod = qi * qk[(size_t)sr*256 + c];
        prod += __shfl_xor(prod, 1);
        prod += __shfl_xor(prod, 2);
        prod += __shfl_xor(prod, 4);
        prod += __shfl_xor(prod, 8);
        float l = prod * 0.25f;       // hd^-0.5 = 1/4
        float mn = fmaxf(m, l);
        float sc = __expf(m - mn);    // 0 on first iter (m = -inf)
        float p  = __expf(l - mn);
        ssum = ssum*sc + p;
        acc  = acc *sc + p * v[(size_t)sr*D + c];
        m = mn;
    }
    out[(size_t)node*D + c] = acc / ssum;
}

extern "C" void kernel_launch(void* const* d_in, const int* in_sizes, int n_in,
                              void* d_out, int out_size, void* d_ws, size_t ws_size,
                              hipStream_t stream)
{
    const float* x     = (const float*)d_in[0];
    const int*   ei    = (const int*)  d_in[1];
    const float* eattr = (const float*)d_in[2];
    const int*   dei   = (const int*)  d_in[3];
    const float* Wv    = (const float*)d_in[4];
    const float* Wqk   = (const float*)d_in[5];
    const float* gW    = (const float*)d_in[6];
    const float* gb    = (const float*)d_in[7];
    const float* groot = (const float*)d_in[8];
    const float* gWe   = (const float*)d_in[9];
    const float* gbe   = (const float*)d_in[10];
    const float* gamma = (const float*)d_in[11];
    const float* beta  = (const float*)d_in[12];
    const float* Wse   = (const float*)d_in[13];
    const float* bse   = (const float*)d_in[14];
    const float* Wout  = (const float*)d_in[15];
    const float* bout  = (const float*)d_in[16];

    const int N = in_sizes[0]/D;
    const int E = in_sizes[1]/2;
    const int L = in_sizes[7]/D;

    float* ws = (float*)d_ws;
    size_t o = 0;
    auto alloc = [&](size_t n){ size_t r = o; o += (n + 63) & ~(size_t)63; return r; };
    size_t f_deg  = alloc((size_t)N);
    size_t f_dis  = alloc((size_t)N);
    size_t f_hcur = alloc((size_t)N*D);    // reused as attention out
    size_t f_hlin = alloc((size_t)N*D);    // reused as x_struct
    size_t f_v    = alloc((size_t)N*D);
    size_t f_xc   = alloc((size_t)N*512);
    size_t f_qk   = alloc((size_t)N*256);
    size_t f_st   = alloc(1024);
    size_t f_w2   = alloc(512*128);
    size_t f_b2   = alloc(128);
    size_t f_cnt  = alloc((size_t)N);      // int: histogram, then cursor
    size_t f_goff = alloc((size_t)N+1);    // int
    size_t f_aoff = alloc((size_t)N+1);    // int
    size_t f_gsrc = alloc((size_t)E);      // int
    size_t f_gedg = alloc((size_t)E);      // int
    size_t f_gnrm = alloc((size_t)E);      // float
    size_t f_asrc = alloc((size_t)E);      // int
    (void)ws_size;

    float* deg  = ws + f_deg;   float* dis  = ws + f_dis;
    float* hcur = ws + f_hcur;  float* hlin = ws + f_hlin;
    float* vbuf = ws + f_v;     float* xc   = ws + f_xc;
    float* qk   = ws + f_qk;    float* stats= ws + f_st;
    float* Wse2 = ws + f_w2;    float* bse2 = ws + f_b2;
    int* cnt  = (int*)(ws + f_cnt);
    int* goff = (int*)(ws + f_goff);
    int* aoff = (int*)(ws + f_aoff);
    int* gsrc = (int*)(ws + f_gsrc);
    int* gedge= (int*)(ws + f_gedg);
    float* gnorm = ws + f_gnrm;
    int* asrc = (int*)(ws + f_asrc);

    const int* e_row = ei;        const int* e_col = ei + E;
    const int* a_src = dei;       const int* a_dst = dei + E;

    dim3 blk256(256);
    int gE = (E+255)/256, gN = (N+255)/256;

    // ---- degree + norm ----
    hipMemsetAsync(deg, 0, (size_t)N*sizeof(float), stream);
    deg_count<<<gE, blk256, 0, stream>>>(e_row, E, deg);
    deg_fin<<<gN, blk256, 0, stream>>>(deg, dis, N);

    // ---- GCN CSR (by col) ----
    hipMemsetAsync(cnt, 0, (size_t)N*sizeof(int), stream);
    hist_int<<<gE, blk256, 0, stream>>>(e_col, E, cnt);
    scan_excl<<<1, 1024, 0, stream>>>(cnt, N, goff);
    hipMemsetAsync(cnt, 0, (size_t)N*sizeof(int), stream);
    scatter_gcn<<<gE, blk256, 0, stream>>>(e_row, e_col, E, goff, cnt, dis, gsrc, gedge, gnorm);

    // ---- attention CSR (by dst) ----
    hipMemsetAsync(cnt, 0, (size_t)N*sizeof(int), stream);
    hist_int<<<gE, blk256, 0, stream>>>(a_dst, E, cnt);
    scan_excl<<<1, 1024, 0, stream>>>(cnt, N, aoff);
    hipMemsetAsync(cnt, 0, (size_t)N*sizeof(int), stream);
    scatter_attn<<<gE, blk256, 0, stream>>>(a_src, a_dst, E, aoff, cnt, asrc);

    // ---- xc block 0 = x ----
    copy_x_to_xc<<<((size_t)N*D+255)/256, blk256, 0, stream>>>(x, xc, N);

    // ---- GCN layers ----
    const float* hin = x;
    for(int l = 0; l < L; l++){
        dim3 g(D/64, (N+63)/64);
        gemm_bias<<<g, blk256, 0, stream>>>(hin, gW + (size_t)l*D*D, gb + (size_t)l*D,
                                            hlin, N, D, D);
        gcn_gather<<<N, 128, 0, stream>>>(hlin, goff, gsrc, gedge, gnorm,
                                          eattr, gWe + (size_t)l*EDIMC*D, gbe + (size_t)l*D,
                                          groot + (size_t)l*D, deg, xc, hcur, l+1);
        hin = hcur;
    }

    // ---- BN stats + fold into W_se ----
    hipMemsetAsync(stats, 0, 1024*sizeof(float), stream);
    bn_stats<<<256, blk256, 0, stream>>>(xc, N, stats);
    float Ninv = 1.0f/(float)N;
    fold_wse<<<512, 128, 0, stream>>>(Wse, gamma, stats, Ninv, Wse2);
    fold_bse<<<1, 128, 0, stream>>>(Wse, gamma, beta, bse, stats, Ninv, bse2);

    // ---- projections ----
    {   // x_struct = xc @ Wse2 + bse2  (into hlin)
        dim3 g(D/64, (N+63)/64);
        gemm_bias<<<g, blk256, 0, stream>>>(xc, Wse2, bse2, hlin, N, 512, D);
    }
    {   // v = x @ Wv
        dim3 g(D/64, (N+63)/64);
        gemm_bias<<<g, blk256, 0, stream>>>(x, Wv, nullptr, vbuf, N, D, D);
    }
    {   // qk = x_struct @ Wqk
        dim3 g(256/64, (N+63)/64);
        gemm_bias<<<g, blk256, 0, stream>>>(hlin, Wqk, nullptr, qk, N, D, 256);
    }

    // ---- fused attention ----
    attn_fused<<<N, 128, 0, stream>>>(qk, vbuf, aoff, asrc, hcur, N);

    // ---- out = attn_out @ Wout + bout ----
    {
        dim3 g(D/64, (N+63)/64);
        gemm_bias<<<g, blk256, 0, stream>>>(hcur, Wout, bout, (float*)d_out, N, D, D);
    }
}